// Round 16
// baseline (84.590 us; speedup 1.0000x reference)
//
#include <hip/hip_runtime.h>
#include <hip/hip_bf16.h>
#include <stdint.h>

// Problem constants: B=2, T=2048, D=1024, H=16, W=256, HD=64; M = B*T = 4096.

typedef __attribute__((ext_vector_type(8))) short short8;
typedef __attribute__((ext_vector_type(4))) float f32x4;

#define MFMA16(a, b, c) __builtin_amdgcn_mfma_f32_16x16x32_bf16((a), (b), (c), 0, 0, 0)

static __device__ __forceinline__ void gl_lds16(const void* g, void* l) {
  __builtin_amdgcn_global_load_lds(
      (const __attribute__((address_space(1))) unsigned int*)g,
      (__attribute__((address_space(3))) unsigned int*)l, 16, 0, 0);
}

#define LGKM0 do { asm volatile("s_waitcnt lgkmcnt(0)" ::: "memory"); \
                   __builtin_amdgcn_sched_barrier(0); } while (0)
#define BARM do { asm volatile("" ::: "memory"); \
                  __builtin_amdgcn_s_barrier(); \
                  asm volatile("" ::: "memory"); } while (0)

static __device__ __forceinline__ uint32_t pkbf(float x, float y) {
  union { __hip_bfloat16 h; uint16_t u; } a, b;
  a.h = __float2bfloat16(x);
  b.h = __float2bfloat16(y);
  return (uint32_t)a.u | ((uint32_t)b.u << 16);
}

static __device__ __forceinline__ short8 cvt8(float4 lo, float4 hi) {
  union { short8 s; __hip_bfloat16 h[8]; } u;
  u.h[0] = __float2bfloat16(lo.x); u.h[1] = __float2bfloat16(lo.y);
  u.h[2] = __float2bfloat16(lo.z); u.h[3] = __float2bfloat16(lo.w);
  u.h[4] = __float2bfloat16(hi.x); u.h[5] = __float2bfloat16(hi.y);
  u.h[6] = __float2bfloat16(hi.z); u.h[7] = __float2bfloat16(hi.w);
  return u.s;
}

// ---------------------------------------------------------------- QKV GEMM v7
// Fused fp32->bf16 conversion: A from x (fp32), B from Wqkv (fp32), both
// reg-staged (load 2xfloat4 -> cvt -> ds_write_b128 to linear dest; swizzle
// lives in the per-lane GLOBAL element offset, as before). No gl_lds, no
// vmcnt ledger (compiler tracks load->cvt->write). STAGE INVARIANT: buffer
// t&1 written for t+2 only after the post-compute barrier (all reads
// retired via LGKM0 before MFMA); ds_writes drained (lgkm0) before the
// following barrier.
__global__ __launch_bounds__(512, 4) void gemm_qkv(
    const float* __restrict__ X, const float* __restrict__ WQKV,
    const float* __restrict__ bias,
    __hip_bfloat16* __restrict__ qb, __hip_bfloat16* __restrict__ kb,
    __hip_bfloat16* __restrict__ vt2) {
  __shared__ alignas(128) char smem[81920];
  const int tid = threadIdx.x;
  const int lane = tid & 63, w = tid >> 6;
  const int wm = w >> 2, wn = w & 3;
  const int r = lane & 15, g = lane >> 4;
  const int NT = 16;

  const int cpx = gridDim.x >> 3;  // 64
  const int swzb = (blockIdx.x & 7) * cpx + (blockIdx.x >> 3);
  const int bm = swzb >> 4, bn = swzb & 15;

  const int srow = tid >> 3;
  const int e = (tid & 7) ^ ((tid >> 4) & 7);
  const int koff = (e >> 2) * 32 + (e & 3) * 8;
  const float* aF[2];
  const float* bF[3];
#pragma unroll
  for (int U = 0; U < 2; ++U)
    aF[U] = X + (size_t)(bm * 128 + U * 64 + srow) * 1024 + koff;
#pragma unroll
  for (int U = 0; U < 3; ++U)
    bF[U] = WQKV + (size_t)(bn * 192 + U * 64 + srow) * 1024 + koff;
  const int ldst = tid * 16;

  auto STAGE = [&](int tt) {
    char* db = smem + ((tt) & 1) * 40960;
    float4 tA[2][2], tB[3][2];
#pragma unroll
    for (int U = 0; U < 2; ++U) {
      tA[U][0] = *(const float4*)(aF[U] + tt * 64);
      tA[U][1] = *(const float4*)(aF[U] + tt * 64 + 4);
    }
#pragma unroll
    for (int U = 0; U < 3; ++U) {
      tB[U][0] = *(const float4*)(bF[U] + tt * 64);
      tB[U][1] = *(const float4*)(bF[U] + tt * 64 + 4);
    }
#pragma unroll
    for (int U = 0; U < 2; ++U)
      *(short8*)(db + U * 8192 + ldst) = cvt8(tA[U][0], tA[U][1]);
#pragma unroll
    for (int U = 0; U < 3; ++U)
      *(short8*)(db + 16384 + U * 8192 + ldst) = cvt8(tB[U][0], tB[U][1]);
  };

  const int hsw = (r >> 1) & 7;
  const int s0 = ((0 + g) ^ hsw) * 16;
  const int s1 = ((4 + g) ^ hsw) * 16;
  const int rdA = (wm * 64 + r) * 128;
  const int rdB = 16384 + (wn * 48 + r) * 128;

  f32x4 acc[4][3] = {};
  short8 af[4][2], bf[3][2];

  // prologue: stage tiles 0 and 1
  STAGE(0);
  STAGE(1);
  LGKM0;
  BARM;

#pragma unroll 1
  for (int t = 0; t < NT; ++t) {
    const char* cb = smem + (t & 1) * 40960;
#pragma unroll
    for (int i = 0; i < 4; ++i) {
      af[i][0] = *(const short8*)(cb + rdA + i * 2048 + s0);
      af[i][1] = *(const short8*)(cb + rdA + i * 2048 + s1);
    }
#pragma unroll
    for (int j = 0; j < 3; ++j) {
      bf[j][0] = *(const short8*)(cb + rdB + j * 2048 + s0);
      bf[j][1] = *(const short8*)(cb + rdB + j * 2048 + s1);
    }
    LGKM0;  // reads retired before the barrier (stage writes follow it)
    __builtin_amdgcn_s_setprio(1);
#pragma unroll
    for (int i = 0; i < 4; ++i)
#pragma unroll
      for (int j = 0; j < 3; ++j) acc[i][j] = MFMA16(af[i][0], bf[j][0], acc[i][j]);
#pragma unroll
    for (int i = 0; i < 4; ++i)
#pragma unroll
      for (int j = 0; j < 3; ++j) acc[i][j] = MFMA16(af[i][1], bf[j][1], acc[i][j]);
    __builtin_amdgcn_s_setprio(0);
    BARM;  // all waves' reads of buffer t&1 retired
    if (t + 2 < NT) {
      STAGE(t + 2);
      LGKM0;  // ds_writes visible before next barrier
    }
    BARM;
  }

  // ---- epilogue: scatter to q (scaled 1/8), k, v^T(pi-packed) with bias
  float bjv[3];
  const int nb = bn * 192 + wn * 48;
#pragma unroll
  for (int j = 0; j < 3; ++j) bjv[j] = bias[nb + j * 16 + r];
#pragma unroll
  for (int i = 0; i < 4; ++i) {
    const int m0 = bm * 128 + wm * 64 + i * 16 + g * 4;
#pragma unroll
    for (int j = 0; j < 3; ++j) {
      const int nn = nb + j * 16 + r;
      const int c = nn >> 10, h = (nn >> 6) & 15, hd = nn & 63;
      const int b_ = m0 >> 11, t0 = m0 & 2047;
      const size_t hb = (size_t)(b_ * 16 + h);
      if (c == 0) {
#pragma unroll
        for (int q = 0; q < 4; ++q)
          qb[(hb * 2048 + t0 + q) * 64 + hd] =
              __float2bfloat16((acc[i][j][q] + bjv[j]) * 0.125f);
      } else if (c == 1) {
#pragma unroll
        for (int q = 0; q < 4; ++q)
          kb[(hb * 2048 + t0 + q) * 64 + hd] =
              __float2bfloat16(acc[i][j][q] + bjv[j]);
      } else {
        union { uint2 u; __hip_bfloat16 hh[4]; } pk;
#pragma unroll
        for (int q = 0; q < 4; ++q)
          pk.hh[q] = __float2bfloat16(acc[i][j][q] + bjv[j]);
        // pi-packed tile layout: p = g*8 + half*4 (+0..3)
        const int kk = t0 & 31;
        const int pp = ((kk & 12) << 1) + ((kk & 16) >> 2);
        *(uint2*)&vt2[hb * 131072 + (size_t)(t0 >> 5) * 2048 + hd * 32 + pp] =
            pk.u;
      }
    }
  }
}

// ---------------------------------------------------------------- out GEMM v6
// Mixed staging: A (yb, bf16) via gl_lds; B from Wo (fp32) reg-staged with
// fused conversion. B loads issued first so their wait leaves this phase's
// gl_lds in flight; tail vmcnt(0) covers the last gl_lds tiles.
__global__ __launch_bounds__(512, 4) void gemm_out8(
    const __hip_bfloat16* __restrict__ A, const float* __restrict__ WO,
    const float* __restrict__ bias, float* __restrict__ outF) {
  __shared__ alignas(128) char smem[65536];
  const int tid = threadIdx.x;
  const int lane = tid & 63, w = tid >> 6;
  const int wm = w >> 2, wn = w & 3;
  const int r = lane & 15, g = lane >> 4;
  const int K = 1024, NT = 16;

  const int cpx = gridDim.x >> 3;
  const int swzb = (blockIdx.x & 7) * cpx + (blockIdx.x >> 3);
  const int bm = swzb >> 3, bn = swzb & 7;

  const int srow = tid >> 3;
  const int e = (tid & 7) ^ ((tid >> 4) & 7);
  const int koff = (e >> 2) * 32 + (e & 3) * 8;
  const __hip_bfloat16* aU[2];
  const float* bFo[2];
#pragma unroll
  for (int U = 0; U < 2; ++U) {
    aU[U] = A + (size_t)(bm * 128 + U * 64 + srow) * K + koff;
    bFo[U] = WO + (size_t)(bn * 128 + U * 64 + srow) * 1024 + koff;
  }
  const int ldst = tid * 16;

  auto STG = [&](int tt) {
    char* db = smem + ((tt) & 1) * 32768;
    float4 tB[2][2];
#pragma unroll
    for (int U = 0; U < 2; ++U) {
      tB[U][0] = *(const float4*)(bFo[U] + tt * 64);
      tB[U][1] = *(const float4*)(bFo[U] + tt * 64 + 4);
    }
    gl_lds16(aU[0] + tt * 64, db + 0 * 8192 + ldst);
    gl_lds16(aU[1] + tt * 64, db + 1 * 8192 + ldst);
#pragma unroll
    for (int U = 0; U < 2; ++U)
      *(short8*)(db + 16384 + U * 8192 + ldst) = cvt8(tB[U][0], tB[U][1]);
  };

  const int hsw = (r >> 1) & 7;
  const int s0 = ((0 + g) ^ hsw) * 16;
  const int s1 = ((4 + g) ^ hsw) * 16;
  const int rdA = (wm * 64 + r) * 128;
  const int rdB = 16384 + (wn * 32 + r) * 128;

  f32x4 acc[4][2] = {};
  short8 af[4][2], bf[2][2];

  STG(0);
  STG(1);
  asm volatile("s_waitcnt vmcnt(0)" ::: "memory");
  LGKM0;
  BARM;

#pragma unroll 1
  for (int t = 0; t < NT; ++t) {
    const char* cb = smem + (t & 1) * 32768;
#pragma unroll
    for (int i = 0; i < 4; ++i) {
      af[i][0] = *(const short8*)(cb + rdA + i * 2048 + s0);
      af[i][1] = *(const short8*)(cb + rdA + i * 2048 + s1);
    }
#pragma unroll
    for (int j = 0; j < 2; ++j) {
      bf[j][0] = *(const short8*)(cb + rdB + j * 2048 + s0);
      bf[j][1] = *(const short8*)(cb + rdB + j * 2048 + s1);
    }
    LGKM0;
    __builtin_amdgcn_s_setprio(1);
#pragma unroll
    for (int i = 0; i < 4; ++i)
#pragma unroll
      for (int j = 0; j < 2; ++j) acc[i][j] = MFMA16(af[i][0], bf[j][0], acc[i][j]);
#pragma unroll
    for (int i = 0; i < 4; ++i)
#pragma unroll
      for (int j = 0; j < 2; ++j) acc[i][j] = MFMA16(af[i][1], bf[j][1], acc[i][j]);
    __builtin_amdgcn_s_setprio(0);
    BARM;  // all reads of buffer t&1 retired
    if (t + 2 < NT) {
      STG(t + 2);  // B-wait inside forces older (t's) gl_lds complete
      LGKM0;
    } else if (t + 1 < NT) {
      asm volatile("s_waitcnt vmcnt(0)" ::: "memory");  // drain last gl_lds
    }
    BARM;
  }

  float bjv[2];
  const int nb = bn * 128 + wn * 32;
#pragma unroll
  for (int j = 0; j < 2; ++j) bjv[j] = bias[nb + j * 16 + r];
#pragma unroll
  for (int i = 0; i < 4; ++i) {
    const int m0 = bm * 128 + wm * 64 + i * 16 + g * 4;
#pragma unroll
    for (int j = 0; j < 2; ++j) {
      const int nn = nb + j * 16 + r;
#pragma unroll
      for (int q = 0; q < 4; ++q)
        outF[(size_t)(m0 + q) * 1024 + nn] = acc[i][j][q] + bjv[j];
    }
  }
}

// ---------------------------------------------------------------- attention v7
// (unchanged from R14)
__global__ __launch_bounds__(512, 6) void attn_local(
    const __hip_bfloat16* __restrict__ qb, const __hip_bfloat16* __restrict__ kb,
    const __hip_bfloat16* __restrict__ vt2, __hip_bfloat16* __restrict__ yb) {
  __shared__ alignas(16) char smem[49152];  // 12 K-tiles x 4KB
  const int xcd = blockIdx.x & 7;
  const int idx = blockIdx.x >> 3;          // 0..63
  const int bh = xcd + (idx >> 4) * 8;      // b*16 + h
  const int qt = idx & 15;                  // 128-row q-tile
  const int tid = threadIdx.x;
  const int w = tid >> 6, lane = tid & 63;
  const int r = lane & 15, g = lane >> 4;
  const int qa = qt * 128 + w * 16;

  const __hip_bfloat16* qp = qb + (size_t)bh * 2048 * 64;
  const __hip_bfloat16* kp = kb + (size_t)bh * 2048 * 64;
  const __hip_bfloat16* vpb = vt2 + (size_t)bh * 131072 + r * 32 + g * 8;

  const int t_lo = (qt >= 2) ? (4 * qt - 8) : 0;
  const int t_hi = 4 * qt + 3;
  const int nunits = (t_hi - t_lo + 1) << 8;  // 16B units
#pragma unroll
  for (int rr = 0; rr < 6; ++rr) {
    const int u = rr * 512 + tid;
    if (u < nunits) {
      const int tt = u >> 8, row = (u >> 3) & 31, sl = u & 7;
      gl_lds16(kp + (size_t)((t_lo + tt) * 32 + row) * 64 + (sl ^ (row & 7)) * 8,
               smem + u * 16);
    }
  }

  const short8 qf0 = *(const short8*)&qp[(qa + r) * 64 + g * 8];
  const short8 qf1 = *(const short8*)&qp[(qa + r) * 64 + g * 8 + 32];

  asm volatile("s_waitcnt vmcnt(0)" ::: "memory");
  __syncthreads();

  f32x4 acc[4] = {};
  float m = -1e30f;
  float lsum = 0.f;

  const int wlo = ((qa >= 256) ? ((qa - 255) >> 5) : 0) - t_lo;
  const int whi = ((qa + 15) >> 5) - t_lo;
  const int xsw = (r & 7) << 4;

#pragma unroll 1
  for (int tt = wlo; tt <= whi; ++tt) {
    const int tabs = t_lo + tt;
    const int kbase = tabs << 5;
    const short8 v0 = *(const short8*)(vpb + (size_t)tabs * 2048);
    const short8 v1 = *(const short8*)(vpb + (size_t)tabs * 2048 + 512);
    const short8 v2 = *(const short8*)(vpb + (size_t)tabs * 2048 + 1024);
    const short8 v3 = *(const short8*)(vpb + (size_t)tabs * 2048 + 1536);
    const char* kt = smem + tt * 4096;
    const short8 k00 = *(const short8*)(kt + r * 128 + (((g) << 4) ^ xsw));
    const short8 k01 = *(const short8*)(kt + r * 128 + (((4 + g) << 4) ^ xsw));
    const short8 k10 = *(const short8*)(kt + (16 + r) * 128 + (((g) << 4) ^ xsw));
    const short8 k11 = *(const short8*)(kt + (16 + r) * 128 + (((4 + g) << 4) ^ xsw));
    f32x4 st0 = {}, st1 = {};
    __builtin_amdgcn_s_setprio(1);
    st0 = MFMA16(k00, qf0, st0);
    st0 = MFMA16(k01, qf1, st0);
    st1 = MFMA16(k10, qf0, st1);
    st1 = MFMA16(k11, qf1, st1);
    __builtin_amdgcn_s_setprio(0);
    float sv[2][4];
#pragma unroll
    for (int q = 0; q < 4; ++q) {
      const unsigned d0 = (unsigned)(qa + r) - (unsigned)(kbase + g * 4 + q);
      const unsigned d1 = (unsigned)(qa + r) - (unsigned)(kbase + 16 + g * 4 + q);
      sv[0][q] = (d0 <= 255u) ? st0[q] : -1e30f;
      sv[1][q] = (d1 <= 255u) ? st1[q] : -1e30f;
    }
    const float tmax = fmaxf(
        fmaxf(fmaxf(sv[0][0], sv[0][1]), fmaxf(sv[0][2], sv[0][3])),
        fmaxf(fmaxf(sv[1][0], sv[1][1]), fmaxf(sv[1][2], sv[1][3])));
    if (!__all(tmax <= m + 8.f)) {
      float rm = tmax;
      rm = fmaxf(rm, __shfl_xor(rm, 16));
      rm = fmaxf(rm, __shfl_xor(rm, 32));
      const float mnew = fmaxf(m, rm);
      const float fac = __expf(m - mnew);
      m = mnew;
      lsum *= fac;
      acc[0] *= fac; acc[1] *= fac; acc[2] *= fac; acc[3] *= fac;
    }
    float p[2][4];
#pragma unroll
    for (int f = 0; f < 2; ++f)
#pragma unroll
      for (int q = 0; q < 4; ++q) {
        p[f][q] = __expf(sv[f][q] - m);
        lsum += p[f][q];
      }
    union { short8 s; uint32_t u[4]; } pb;
    pb.u[0] = pkbf(p[0][0], p[0][1]);
    pb.u[1] = pkbf(p[0][2], p[0][3]);
    pb.u[2] = pkbf(p[1][0], p[1][1]);
    pb.u[3] = pkbf(p[1][2], p[1][3]);
    __builtin_amdgcn_s_setprio(1);
    acc[0] = MFMA16(v0, pb.s, acc[0]);
    acc[1] = MFMA16(v1, pb.s, acc[1]);
    acc[2] = MFMA16(v2, pb.s, acc[2]);
    acc[3] = MFMA16(v3, pb.s, acc[3]);
    __builtin_amdgcn_s_setprio(0);
  }

  lsum += __shfl_xor(lsum, 16);
  lsum += __shfl_xor(lsum, 32);
  const float inv = 1.f / lsum;

  const int b_ = bh >> 4, h = bh & 15;
  __hip_bfloat16* yrow = yb + (size_t)(b_ * 2048 + qa + r) * 1024 + h * 64;
#pragma unroll
  for (int u = 0; u < 4; ++u) {
    union { uint2 uu; __hip_bfloat16 hh[4]; } pk;
#pragma unroll
    for (int q = 0; q < 4; ++q) pk.hh[q] = __float2bfloat16(acc[u][q] * inv);
    *(uint2*)&yrow[u * 16 + g * 4] = pk.uu;
  }
}

// ---------------------------------------------------------------- launch
extern "C" void kernel_launch(void* const* d_in, const int* in_sizes, int n_in,
                              void* d_out, int out_size, void* d_ws,
                              size_t ws_size, hipStream_t stream) {
  const float* x = (const float*)d_in[0];
  const float* Wqkv = (const float*)d_in[1];
  const float* bqkv = (const float*)d_in[2];
  const float* Wo = (const float*)d_in[3];
  const float* bo = (const float*)d_in[4];
  float* out = (float*)d_out;

  char* ws = (char*)d_ws;
  __hip_bfloat16* qb = (__hip_bfloat16*)(ws + 0);                    // 8 MB
  __hip_bfloat16* kb = (__hip_bfloat16*)(ws + 8388608);              // 8 MB
  __hip_bfloat16* vt2 = (__hip_bfloat16*)(ws + 16777216);            // 8 MB
  __hip_bfloat16* yb = (__hip_bfloat16*)(ws + 25165824);             // 8 MB

  // QKV (+ fused fp32->bf16): M=4096, N=3072, K=1024 -> 512 blocks (2/CU)
  gemm_qkv<<<512, 512, 0, stream>>>(x, Wqkv, bqkv, qb, kb, vt2);
  // attention: 8 XCD x 4 heads x 16 q-tiles of 128 rows
  attn_local<<<512, 512, 0, stream>>>(qb, kb, vt2, yb);
  // out (+ fused Wo conversion): M=4096, N=1024, K=1024 -> 256 blocks
  gemm_out8<<<256, 512, 0, stream>>>(yb, Wo, bo, out);
}

// Round 17
// 71.292 us; speedup vs baseline: 1.1865x; 1.1865x over previous
//
#include <hip/hip_runtime.h>
#include <hip/hip_bf16.h>
#include <stdint.h>

// Problem constants: B=2, T=2048, D=1024, H=16, W=256, HD=64; M = B*T = 4096.

typedef __attribute__((ext_vector_type(8))) short short8;
typedef __attribute__((ext_vector_type(4))) float f32x4;

#define MFMA16(a, b, c) __builtin_amdgcn_mfma_f32_16x16x32_bf16((a), (b), (c), 0, 0, 0)

static __device__ __forceinline__ void gl_lds16(const void* g, void* l) {
  __builtin_amdgcn_global_load_lds(
      (const __attribute__((address_space(1))) unsigned int*)g,
      (__attribute__((address_space(3))) unsigned int*)l, 16, 0, 0);
}

#define BARM do { asm volatile("" ::: "memory"); \
                  __builtin_amdgcn_s_barrier(); \
                  asm volatile("" ::: "memory"); } while (0)

static __device__ __forceinline__ uint32_t pkbf(float x, float y) {
  union { __hip_bfloat16 h; uint16_t u; } a, b;
  a.h = __float2bfloat16(x);
  b.h = __float2bfloat16(y);
  return (uint32_t)a.u | ((uint32_t)b.u << 16);
}

// ---------------------------------------------------------------- convert all
__global__ void cvt_all(const float* __restrict__ x, const float* __restrict__ wqkv,
                        const float* __restrict__ wo, __hip_bfloat16* __restrict__ xb,
                        __hip_bfloat16* __restrict__ wqkvb,
                        __hip_bfloat16* __restrict__ wob) {
  const int N0 = 524288, N1 = 393216, N2 = 131072;  // granules of 8 floats
  int i = blockIdx.x * blockDim.x + threadIdx.x;
  const int stride = gridDim.x * blockDim.x;
  for (; i < N0 + N1 + N2; i += stride) {
    const float* in;
    __hip_bfloat16* out;
    int gidx;
    if (i < N0) { in = x; out = xb; gidx = i; }
    else if (i < N0 + N1) { in = wqkv; out = wqkvb; gidx = i - N0; }
    else { in = wo; out = wob; gidx = i - N0 - N1; }
    const float4* p = (const float4*)in + (size_t)gidx * 2;
    float4 v0 = p[0], v1 = p[1];
    union { short8 s; __hip_bfloat16 h[8]; } u;
    u.h[0] = __float2bfloat16(v0.x); u.h[1] = __float2bfloat16(v0.y);
    u.h[2] = __float2bfloat16(v0.z); u.h[3] = __float2bfloat16(v0.w);
    u.h[4] = __float2bfloat16(v1.x); u.h[5] = __float2bfloat16(v1.y);
    u.h[6] = __float2bfloat16(v1.z); u.h[7] = __float2bfloat16(v1.w);
    ((short8*)out)[gidx] = u.s;
  }
}

// ---------------------------------------------------------------- QKV GEMM v6
// (R14 exactly: gl_lds staging, 2 sync points/tile, no explicit lgkm drain)
__global__ __launch_bounds__(512, 4) void gemm_qkv(
    const __hip_bfloat16* __restrict__ A, const __hip_bfloat16* __restrict__ Bm,
    const float* __restrict__ bias,
    __hip_bfloat16* __restrict__ qb, __hip_bfloat16* __restrict__ kb,
    __hip_bfloat16* __restrict__ vt2) {
  __shared__ alignas(128) char smem[81920];
  const int tid = threadIdx.x;
  const int lane = tid & 63, w = tid >> 6;
  const int wm = w >> 2, wn = w & 3;
  const int r = lane & 15, g = lane >> 4;
  const int K = 1024, NT = 16;

  const int cpx = gridDim.x >> 3;  // 64
  const int swzb = (blockIdx.x & 7) * cpx + (blockIdx.x >> 3);
  const int bm = swzb >> 4, bn = swzb & 15;

  const int srow = tid >> 3;
  const int e = (tid & 7) ^ ((tid >> 4) & 7);
  const int koff = (e >> 2) * 32 + (e & 3) * 8;
  const __hip_bfloat16* aU[2];
  const __hip_bfloat16* bU[3];
#pragma unroll
  for (int U = 0; U < 2; ++U)
    aU[U] = A + (size_t)(bm * 128 + U * 64 + srow) * K + koff;
#pragma unroll
  for (int U = 0; U < 3; ++U)
    bU[U] = Bm + (size_t)(bn * 192 + U * 64 + srow) * K + koff;
  const int ldst = tid * 16;

#define STA(t, U) gl_lds16(aU[U] + (t) * 64, smem + ((t) & 1) * 40960 + (U) * 8192 + ldst)
#define STB(t, U) gl_lds16(bU[U] + (t) * 64, smem + ((t) & 1) * 40960 + 16384 + (U) * 8192 + ldst)

  const int hsw = (r >> 1) & 7;
  const int s0 = ((0 + g) ^ hsw) * 16;
  const int s1 = ((4 + g) ^ hsw) * 16;
  const int rdA = (wm * 64 + r) * 128;
  const int rdB = 16384 + (wn * 48 + r) * 128;

  f32x4 acc[4][3] = {};
  short8 af[4][2], bf[3][2];

  STA(0, 0); STA(0, 1); STB(0, 0); STB(0, 1); STB(0, 2);
  STA(1, 0); STA(1, 1); STB(1, 0); STB(1, 1); STB(1, 2);
  asm volatile("s_waitcnt vmcnt(5)" ::: "memory");
  BARM;

#pragma unroll 1
  for (int t = 0; t < NT; ++t) {
    const char* cb = smem + (t & 1) * 40960;
#pragma unroll
    for (int i = 0; i < 4; ++i) {
      af[i][0] = *(const short8*)(cb + rdA + i * 2048 + s0);
      af[i][1] = *(const short8*)(cb + rdA + i * 2048 + s1);
    }
#pragma unroll
    for (int j = 0; j < 3; ++j) {
      bf[j][0] = *(const short8*)(cb + rdB + j * 2048 + s0);
      bf[j][1] = *(const short8*)(cb + rdB + j * 2048 + s1);
    }
    __builtin_amdgcn_s_setprio(1);
#pragma unroll
    for (int i = 0; i < 4; ++i)
#pragma unroll
      for (int j = 0; j < 3; ++j) acc[i][j] = MFMA16(af[i][0], bf[j][0], acc[i][j]);
#pragma unroll
    for (int i = 0; i < 4; ++i)
#pragma unroll
      for (int j = 0; j < 3; ++j) acc[i][j] = MFMA16(af[i][1], bf[j][1], acc[i][j]);
    __builtin_amdgcn_s_setprio(0);
    BARM;  // all waves' reads of buffer t&1 retired
    if (t + 2 < NT) {
      STB(t + 2, 0); STB(t + 2, 1); STB(t + 2, 2);
      STA(t + 2, 0); STA(t + 2, 1);
      asm volatile("s_waitcnt vmcnt(5)" ::: "memory");
    } else if (t + 1 < NT) {
      asm volatile("s_waitcnt vmcnt(0)" ::: "memory");
    }
    BARM;
  }
#undef STA
#undef STB

  float bjv[3];
  const int nb = bn * 192 + wn * 48;
#pragma unroll
  for (int j = 0; j < 3; ++j) bjv[j] = bias[nb + j * 16 + r];
#pragma unroll
  for (int i = 0; i < 4; ++i) {
    const int m0 = bm * 128 + wm * 64 + i * 16 + g * 4;
#pragma unroll
    for (int j = 0; j < 3; ++j) {
      const int nn = nb + j * 16 + r;
      const int c = nn >> 10, h = (nn >> 6) & 15, hd = nn & 63;
      const int b_ = m0 >> 11, t0 = m0 & 2047;
      const size_t hb = (size_t)(b_ * 16 + h);
      if (c == 0) {
#pragma unroll
        for (int q = 0; q < 4; ++q)
          qb[(hb * 2048 + t0 + q) * 64 + hd] =
              __float2bfloat16((acc[i][j][q] + bjv[j]) * 0.125f);
      } else if (c == 1) {
#pragma unroll
        for (int q = 0; q < 4; ++q)
          kb[(hb * 2048 + t0 + q) * 64 + hd] =
              __float2bfloat16(acc[i][j][q] + bjv[j]);
      } else {
        union { uint2 u; __hip_bfloat16 hh[4]; } pk;
#pragma unroll
        for (int q = 0; q < 4; ++q)
          pk.hh[q] = __float2bfloat16(acc[i][j][q] + bjv[j]);
        // pi-packed tile layout: p = g*8 + half*4 (+0..3)
        const int kk = t0 & 31;
        const int pp = ((kk & 12) << 1) + ((kk & 16) >> 2);
        *(uint2*)&vt2[hb * 131072 + (size_t)(t0 >> 5) * 2048 + hd * 32 + pp] =
            pk.u;
      }
    }
  }
}

// ---------------------------------------------------------------- out GEMM v5
// (R14 exactly)
__global__ __launch_bounds__(512, 4) void gemm_out8(
    const __hip_bfloat16* __restrict__ A, const __hip_bfloat16* __restrict__ Bm,
    const float* __restrict__ bias, float* __restrict__ outF) {
  __shared__ alignas(128) char smem[65536];
  const int tid = threadIdx.x;
  const int lane = tid & 63, w = tid >> 6;
  const int wm = w >> 2, wn = w & 3;
  const int r = lane & 15, g = lane >> 4;
  const int K = 1024, NT = 16;

  const int cpx = gridDim.x >> 3;
  const int swzb = (blockIdx.x & 7) * cpx + (blockIdx.x >> 3);
  const int bm = swzb >> 3, bn = swzb & 7;

  const int srow = tid >> 3;
  const int e = (tid & 7) ^ ((tid >> 4) & 7);
  const int koff = (e >> 2) * 32 + (e & 3) * 8;
  const __hip_bfloat16* aU[2];
  const __hip_bfloat16* bU[2];
#pragma unroll
  for (int U = 0; U < 2; ++U) {
    aU[U] = A + (size_t)(bm * 128 + U * 64 + srow) * K + koff;
    bU[U] = Bm + (size_t)(bn * 128 + U * 64 + srow) * K + koff;
  }
  const int ldst = tid * 16;

#define STA(t, U) gl_lds16(aU[U] + (t) * 64, smem + ((t) & 1) * 32768 + (U) * 8192 + ldst)
#define STB(t, U) gl_lds16(bU[U] + (t) * 64, smem + ((t) & 1) * 32768 + 16384 + (U) * 8192 + ldst)

  const int hsw = (r >> 1) & 7;
  const int s0 = ((0 + g) ^ hsw) * 16;
  const int s1 = ((4 + g) ^ hsw) * 16;
  const int rdA = (wm * 64 + r) * 128;
  const int rdB = 16384 + (wn * 32 + r) * 128;

  f32x4 acc[4][2] = {};
  short8 af[4][2], bf[2][2];

  STA(0, 0); STA(0, 1); STB(0, 0); STB(0, 1);
  STA(1, 0); STA(1, 1); STB(1, 0); STB(1, 1);
  asm volatile("s_waitcnt vmcnt(4)" ::: "memory");
  BARM;

#pragma unroll 1
  for (int t = 0; t < NT; ++t) {
    const char* cb = smem + (t & 1) * 32768;
#pragma unroll
    for (int i = 0; i < 4; ++i) {
      af[i][0] = *(const short8*)(cb + rdA + i * 2048 + s0);
      af[i][1] = *(const short8*)(cb + rdA + i * 2048 + s1);
    }
#pragma unroll
    for (int j = 0; j < 2; ++j) {
      bf[j][0] = *(const short8*)(cb + rdB + j * 2048 + s0);
      bf[j][1] = *(const short8*)(cb + rdB + j * 2048 + s1);
    }
    __builtin_amdgcn_s_setprio(1);
#pragma unroll
    for (int i = 0; i < 4; ++i)
#pragma unroll
      for (int j = 0; j < 2; ++j) acc[i][j] = MFMA16(af[i][0], bf[j][0], acc[i][j]);
#pragma unroll
    for (int i = 0; i < 4; ++i)
#pragma unroll
      for (int j = 0; j < 2; ++j) acc[i][j] = MFMA16(af[i][1], bf[j][1], acc[i][j]);
    __builtin_amdgcn_s_setprio(0);
    BARM;  // all reads of buffer t&1 retired
    if (t + 2 < NT) {
      STB(t + 2, 0); STB(t + 2, 1);
      STA(t + 2, 0); STA(t + 2, 1);
      asm volatile("s_waitcnt vmcnt(4)" ::: "memory");
    } else if (t + 1 < NT) {
      asm volatile("s_waitcnt vmcnt(0)" ::: "memory");
    }
    BARM;
  }
#undef STA
#undef STB

  float bjv[2];
  const int nb = bn * 128 + wn * 32;
#pragma unroll
  for (int j = 0; j < 2; ++j) bjv[j] = bias[nb + j * 16 + r];
#pragma unroll
  for (int i = 0; i < 4; ++i) {
    const int m0 = bm * 128 + wm * 64 + i * 16 + g * 4;
#pragma unroll
    for (int j = 0; j < 2; ++j) {
      const int nn = nb + j * 16 + r;
#pragma unroll
      for (int q = 0; q < 4; ++q)
        outF[(size_t)(m0 + q) * 1024 + nn] = acc[i][j][q] + bjv[j];
    }
  }
}

// ---------------------------------------------------------------- attention v7
// (R14 exactly)
__global__ __launch_bounds__(512, 6) void attn_local(
    const __hip_bfloat16* __restrict__ qb, const __hip_bfloat16* __restrict__ kb,
    const __hip_bfloat16* __restrict__ vt2, __hip_bfloat16* __restrict__ yb) {
  __shared__ alignas(16) char smem[49152];  // 12 K-tiles x 4KB
  const int xcd = blockIdx.x & 7;
  const int idx = blockIdx.x >> 3;          // 0..63
  const int bh = xcd + (idx >> 4) * 8;      // b*16 + h
  const int qt = idx & 15;                  // 128-row q-tile
  const int tid = threadIdx.x;
  const int w = tid >> 6, lane = tid & 63;
  const int r = lane & 15, g = lane >> 4;
  const int qa = qt * 128 + w * 16;

  const __hip_bfloat16* qp = qb + (size_t)bh * 2048 * 64;
  const __hip_bfloat16* kp = kb + (size_t)bh * 2048 * 64;
  const __hip_bfloat16* vpb = vt2 + (size_t)bh * 131072 + r * 32 + g * 8;

  const int t_lo = (qt >= 2) ? (4 * qt - 8) : 0;
  const int t_hi = 4 * qt + 3;
  const int nunits = (t_hi - t_lo + 1) << 8;  // 16B units
#pragma unroll
  for (int rr = 0; rr < 6; ++rr) {
    const int u = rr * 512 + tid;
    if (u < nunits) {
      const int tt = u >> 8, row = (u >> 3) & 31, sl = u & 7;
      gl_lds16(kp + (size_t)((t_lo + tt) * 32 + row) * 64 + (sl ^ (row & 7)) * 8,
               smem + u * 16);
    }
  }

  const short8 qf0 = *(const short8*)&qp[(qa + r) * 64 + g * 8];
  const short8 qf1 = *(const short8*)&qp[(qa + r) * 64 + g * 8 + 32];

  asm volatile("s_waitcnt vmcnt(0)" ::: "memory");
  __syncthreads();

  f32x4 acc[4] = {};
  float m = -1e30f;
  float lsum = 0.f;

  const int wlo = ((qa >= 256) ? ((qa - 255) >> 5) : 0) - t_lo;
  const int whi = ((qa + 15) >> 5) - t_lo;
  const int xsw = (r & 7) << 4;

#pragma unroll 1
  for (int tt = wlo; tt <= whi; ++tt) {
    const int tabs = t_lo + tt;
    const int kbase = tabs << 5;
    const short8 v0 = *(const short8*)(vpb + (size_t)tabs * 2048);
    const short8 v1 = *(const short8*)(vpb + (size_t)tabs * 2048 + 512);
    const short8 v2 = *(const short8*)(vpb + (size_t)tabs * 2048 + 1024);
    const short8 v3 = *(const short8*)(vpb + (size_t)tabs * 2048 + 1536);
    const char* kt = smem + tt * 4096;
    const short8 k00 = *(const short8*)(kt + r * 128 + (((g) << 4) ^ xsw));
    const short8 k01 = *(const short8*)(kt + r * 128 + (((4 + g) << 4) ^ xsw));
    const short8 k10 = *(const short8*)(kt + (16 + r) * 128 + (((g) << 4) ^ xsw));
    const short8 k11 = *(const short8*)(kt + (16 + r) * 128 + (((4 + g) << 4) ^ xsw));
    f32x4 st0 = {}, st1 = {};
    __builtin_amdgcn_s_setprio(1);
    st0 = MFMA16(k00, qf0, st0);
    st0 = MFMA16(k01, qf1, st0);
    st1 = MFMA16(k10, qf0, st1);
    st1 = MFMA16(k11, qf1, st1);
    __builtin_amdgcn_s_setprio(0);
    float sv[2][4];
#pragma unroll
    for (int q = 0; q < 4; ++q) {
      const unsigned d0 = (unsigned)(qa + r) - (unsigned)(kbase + g * 4 + q);
      const unsigned d1 = (unsigned)(qa + r) - (unsigned)(kbase + 16 + g * 4 + q);
      sv[0][q] = (d0 <= 255u) ? st0[q] : -1e30f;
      sv[1][q] = (d1 <= 255u) ? st1[q] : -1e30f;
    }
    const float tmax = fmaxf(
        fmaxf(fmaxf(sv[0][0], sv[0][1]), fmaxf(sv[0][2], sv[0][3])),
        fmaxf(fmaxf(sv[1][0], sv[1][1]), fmaxf(sv[1][2], sv[1][3])));
    if (!__all(tmax <= m + 8.f)) {
      float rm = tmax;
      rm = fmaxf(rm, __shfl_xor(rm, 16));
      rm = fmaxf(rm, __shfl_xor(rm, 32));
      const float mnew = fmaxf(m, rm);
      const float fac = __expf(m - mnew);
      m = mnew;
      lsum *= fac;
      acc[0] *= fac; acc[1] *= fac; acc[2] *= fac; acc[3] *= fac;
    }
    float p[2][4];
#pragma unroll
    for (int f = 0; f < 2; ++f)
#pragma unroll
      for (int q = 0; q < 4; ++q) {
        p[f][q] = __expf(sv[f][q] - m);
        lsum += p[f][q];
      }
    union { short8 s; uint32_t u[4]; } pb;
    pb.u[0] = pkbf(p[0][0], p[0][1]);
    pb.u[1] = pkbf(p[0][2], p[0][3]);
    pb.u[2] = pkbf(p[1][0], p[1][1]);
    pb.u[3] = pkbf(p[1][2], p[1][3]);
    __builtin_amdgcn_s_setprio(1);
    acc[0] = MFMA16(v0, pb.s, acc[0]);
    acc[1] = MFMA16(v1, pb.s, acc[1]);
    acc[2] = MFMA16(v2, pb.s, acc[2]);
    acc[3] = MFMA16(v3, pb.s, acc[3]);
    __builtin_amdgcn_s_setprio(0);
  }

  lsum += __shfl_xor(lsum, 16);
  lsum += __shfl_xor(lsum, 32);
  const float inv = 1.f / lsum;

  const int b_ = bh >> 4, h = bh & 15;
  __hip_bfloat16* yrow = yb + (size_t)(b_ * 2048 + qa + r) * 1024 + h * 64;
#pragma unroll
  for (int u = 0; u < 4; ++u) {
    union { uint2 uu; __hip_bfloat16 hh[4]; } pk;
#pragma unroll
    for (int q = 0; q < 4; ++q) pk.hh[q] = __float2bfloat16(acc[u][q] * inv);
    *(uint2*)&yrow[u * 16 + g * 4] = pk.uu;
  }
}

// ---------------------------------------------------------------- launch
extern "C" void kernel_launch(void* const* d_in, const int* in_sizes, int n_in,
                              void* d_out, int out_size, void* d_ws,
                              size_t ws_size, hipStream_t stream) {
  const float* x = (const float*)d_in[0];
  const float* Wqkv = (const float*)d_in[1];
  const float* bqkv = (const float*)d_in[2];
  const float* Wo = (const float*)d_in[3];
  const float* bo = (const float*)d_in[4];
  float* out = (float*)d_out;

  char* ws = (char*)d_ws;
  __hip_bfloat16* xb = (__hip_bfloat16*)(ws + 0);                    // 8 MB
  __hip_bfloat16* wqkvb = (__hip_bfloat16*)(ws + 8388608);           // 6 MB
  __hip_bfloat16* wob = (__hip_bfloat16*)(ws + 14680064);            // 2 MB
  __hip_bfloat16* qb = (__hip_bfloat16*)(ws + 16777216);             // 8 MB
  __hip_bfloat16* kb = (__hip_bfloat16*)(ws + 25165824);             // 8 MB
  __hip_bfloat16* vt2 = (__hip_bfloat16*)(ws + 33554432);            // 8 MB
  __hip_bfloat16* yb = (__hip_bfloat16*)(ws + 41943040);             // 8 MB

  cvt_all<<<2048, 256, 0, stream>>>(x, Wqkv, Wo, xb, wqkvb, wob);

  // QKV: M=4096, N=3072, K=1024 -> 32x16 = 512 blocks of 128x192 (2/CU)
  gemm_qkv<<<512, 512, 0, stream>>>(xb, wqkvb, bqkv, qb, kb, vt2);
  // attention: 8 XCD x 4 heads x 16 q-tiles of 128 rows
  attn_local<<<512, 512, 0, stream>>>(qb, kb, vt2, yb);
  // out: M=4096, N=1024, K=1024 -> 32x8 = 256 blocks of 128x128
  gemm_out8<<<256, 512, 0, stream>>>(yb, wob, bo, out);
}